// Round 5
// baseline (661.204 us; speedup 1.0000x reference)
//
#include <hip/hip_runtime.h>
#include <math.h>

#define N_NODES 50000
#define N_EDGES 800000
#define ETOT (N_EDGES + N_NODES)
#define F_IN 128
#define HD 64
#define NHEAD 4
#define HC 256
#define NGRAPH 512
#define NOUT 64
#define LN_EPS 1e-5f

typedef __attribute__((ext_vector_type(8))) short bf16x8;
typedef __attribute__((ext_vector_type(4))) float f32x4;

__device__ __forceinline__ float wave_sum(float v) {
#pragma unroll
    for (int m = 1; m < 64; m <<= 1) v += __shfl_xor(v, m, 64);
    return v;
}
__device__ __forceinline__ float wave_max(float v) {
#pragma unroll
    for (int m = 1; m < 64; m <<= 1) v = fmaxf(v, __shfl_xor(v, m, 64));
    return v;
}
__device__ __forceinline__ float red16(float v) {
    v += __shfl_xor(v, 1, 64);
    v += __shfl_xor(v, 2, 64);
    v += __shfl_xor(v, 4, 64);
    v += __shfl_xor(v, 8, 64);
    return v;
}
__device__ __forceinline__ float gelu_exact(float x) {
    return 0.5f * x * (1.0f + erff(x * 0.70710678118654752f));
}
__device__ __forceinline__ unsigned short f2bf(float x) {
    unsigned int u = __float_as_uint(x);
    return (unsigned short)((u + 0x7fffu + ((u >> 16) & 1u)) >> 16);
}
__device__ __forceinline__ float bf2f(unsigned short u) {
    return __uint_as_float(((unsigned int)u) << 16);
}

// ---------------- CSR build ----------------
__global__ void k_count(const int* __restrict__ ei, int* __restrict__ deg) {
    int t = blockIdx.x * blockDim.x + threadIdx.x;
    if (t >= ETOT) return;
    int dst = (t < N_EDGES) ? ei[N_EDGES + t] : (t - N_EDGES);
    atomicAdd(deg + dst, 1);
}

__global__ void k_scan(const int* __restrict__ deg, int* __restrict__ rowptr,
                       int* __restrict__ cursor) {
    __shared__ int wsum[16];
    __shared__ int chunk_total;
    int tid = threadIdx.x, wid = tid >> 6, lane = tid & 63;
    int carry = 0;
    if (tid == 0) rowptr[0] = 0;
    for (int base = 0; base < N_NODES; base += 1024) {
        int i = base + tid;
        int v = (i < N_NODES) ? deg[i] : 0;
        int incl = v;
#pragma unroll
        for (int off = 1; off < 64; off <<= 1) {
            int t = __shfl_up(incl, off, 64);
            if (lane >= off) incl += t;
        }
        if (lane == 63) wsum[wid] = incl;
        __syncthreads();
        if (wid == 0) {
            int wv = (lane < 16) ? wsum[lane] : 0;
            int wincl = wv;
#pragma unroll
            for (int off = 1; off < 16; off <<= 1) {
                int t = __shfl_up(wincl, off, 64);
                if (lane >= off) wincl += t;
            }
            if (lane < 16) wsum[lane] = wincl - wv;
            if (lane == 15) chunk_total = wincl;
        }
        __syncthreads();
        int total_incl = carry + wsum[wid] + incl;
        if (i < N_NODES) {
            rowptr[i + 1] = total_incl;
            cursor[i] = total_incl - v;
        }
        carry += chunk_total;
        __syncthreads();
    }
}

__global__ void k_fill(const int* __restrict__ ei, int* __restrict__ cursor,
                       int* __restrict__ csr) {
    int t = blockIdx.x * blockDim.x + threadIdx.x;
    if (t >= ETOT) return;
    int src, dst;
    if (t < N_EDGES) { src = ei[t]; dst = ei[N_EDGES + t]; }
    else             { src = t - N_EDGES; dst = src; }
    int p = atomicAdd(cursor + dst, 1);
    csr[p] = src;
}

// ---------------- prep: concat(x, group_emb) -> bf16 [N, 192] ----------------
__global__ void k_prep(const float* __restrict__ x, const int* __restrict__ gid,
                       const float* __restrict__ gt, unsigned short* __restrict__ Ain) {
    int wid = threadIdx.x >> 6, lane = threadIdx.x & 63;
    int node = blockIdx.x * 4 + wid;
    float f0 = x[node * F_IN + lane];
    float f1 = x[node * F_IN + 64 + lane];
    int g = gid[node];
    float f2 = gt[g * HD + lane];
    unsigned short* r = Ain + (size_t)node * 192;
    r[lane] = f2bf(f0);
    r[64 + lane] = f2bf(f1);
    r[128 + lane] = f2bf(f2);
}

// ---------------- pack W [K,N] f32 -> fragment-order bf16 [K/32][N/16][64][8] ----------------
__global__ void k_pack(const float* __restrict__ W, unsigned short* __restrict__ out,
                       int K, int N) {
    int tid = blockIdx.x * blockDim.x + threadIdx.x;
    int NB = N >> 4;
    int total = (K >> 5) * NB * 512;
    if (tid >= total) return;
    int i = tid & 7;
    int l = (tid >> 3) & 63;
    int t2 = tid >> 9;
    int nb = t2 % NB;
    int kt = t2 / NB;
    int k = kt * 32 + ((l >> 4) << 3) + i;
    int n = nb * 16 + (l & 15);
    out[tid] = f2bf(W[k * N + n]);
}

// ---------------- u vectors: u_s[h][k] = sum_c W0[k, h*64+c] * a[h][c] ----------------
__global__ void k_prep_u(const float* __restrict__ W0, const float* __restrict__ as_,
                         const float* __restrict__ ad_, float* __restrict__ us,
                         float* __restrict__ ud) {
    int t = threadIdx.x;
    int h = t >> 6, k = t & 63;
    float ss = 0.f, dd = 0.f;
    for (int c = 0; c < 64; c++) {
        float w = W0[k * 256 + h * 64 + c];
        ss += w * as_[h * 64 + c];
        dd += w * ad_[h * 64 + c];
    }
    us[t] = ss;
    ud[t] = dd;
}

// ---------------- input projection (MFMA): [N,192]@[192,64] -> LN -> GELU -> bf16 ----------------
__global__ void k_proj_in_mma(const unsigned short* __restrict__ A,
                              const unsigned short* __restrict__ Wpk,
                              const float* __restrict__ inb, const float* __restrict__ lng,
                              const float* __restrict__ lnb, unsigned short* __restrict__ h0bf) {
    int wid = threadIdx.x >> 6, lane = threadIdx.x & 63;
    int m0 = blockIdx.x * 64 + wid * 16;
    if (m0 >= N_NODES) return;
    int g16 = lane >> 4, c16 = lane & 15;
    f32x4 acc[4] = {{0,0,0,0},{0,0,0,0},{0,0,0,0},{0,0,0,0}};
#pragma unroll
    for (int kt = 0; kt < 6; kt++) {
        bf16x8 a = *(const bf16x8*)(A + (size_t)(m0 + c16) * 192 + kt * 32 + g16 * 8);
#pragma unroll
        for (int nt = 0; nt < 4; nt++) {
            bf16x8 b = *(const bf16x8*)(Wpk + (((kt * 4 + nt) * 64 + lane) << 3));
            acc[nt] = __builtin_amdgcn_mfma_f32_16x16x32_bf16(a, b, acc[nt], 0, 0, 0);
        }
    }
    float bv[4], gv[4], bb[4];
#pragma unroll
    for (int nt = 0; nt < 4; nt++) {
        int c = nt * 16 + c16;
        bv[nt] = inb[c]; gv[nt] = lng[c]; bb[nt] = lnb[c];
    }
#pragma unroll
    for (int j = 0; j < 4; j++) {
        float d[4], s = 0.f;
#pragma unroll
        for (int nt = 0; nt < 4; nt++) { d[nt] = acc[nt][j] + bv[nt]; s += d[nt]; }
        float mu = red16(s) * (1.0f / 64.0f);
        float v = 0.f;
#pragma unroll
        for (int nt = 0; nt < 4; nt++) { d[nt] -= mu; v += d[nt] * d[nt]; }
        float r = rsqrtf(red16(v) * (1.0f / 64.0f) + LN_EPS);
        int row = m0 + g16 * 4 + j;
#pragma unroll
        for (int nt = 0; nt < 4; nt++) {
            float y = gelu_exact(d[nt] * r * gv[nt] + bb[nt]);
            h0bf[(size_t)row * 64 + nt * 16 + c16] = f2bf(y);
        }
    }
}

// ---------------- layer-0 logits: als[n,h] = h0[n,:]·u_s[h,:] ----------------
__global__ void k_logits(const unsigned short* __restrict__ h0bf, const float* __restrict__ us,
                         const float* __restrict__ ud, float* __restrict__ als,
                         float* __restrict__ ald) {
    int wid = threadIdx.x >> 6, lane = threadIdx.x & 63;
    int g = lane >> 4, l16 = lane & 15;
    int node = blockIdx.x * 16 + wid * 4 + g;
    ushort4 hv = ((const ushort4*)h0bf)[(size_t)node * 16 + l16];
    float v0 = bf2f(hv.x), v1 = bf2f(hv.y), v2 = bf2f(hv.z), v3 = bf2f(hv.w);
#pragma unroll
    for (int h = 0; h < 4; h++) {
        const float* u = us + h * 64 + 4 * l16;
        const float* w = ud + h * 64 + 4 * l16;
        float ps = v0 * u[0] + v1 * u[1] + v2 * u[2] + v3 * u[3];
        float pd = v0 * w[0] + v1 * w[1] + v2 * w[2] + v3 * w[3];
        ps = red16(ps); pd = red16(pd);
        if (l16 == 0) { als[node * 4 + h] = ps; ald[node * 4 + h] = pd; }
    }
}

// ---------------- layer-0 aggregation over h0 (128B/edge), single-pass, no max ----------------
__global__ void k_agg0(const int* __restrict__ rowptr, const int* __restrict__ csr,
                       const unsigned short* __restrict__ h0bf, const float* __restrict__ als,
                       const float* __restrict__ ald, unsigned short* __restrict__ aggbf) {
    __shared__ float4 lacc[2][64];
    __shared__ float lss[2][4];
    int wid = threadIdx.x >> 6, lane = threadIdx.x & 63;
    int nloc = wid >> 1, half = wid & 1;
    int node = blockIdx.x * 2 + nloc;
    int start = rowptr[node], end = rowptr[node + 1];
    int g = lane >> 4, l16 = lane & 15;
    float4 adv = ((const float4*)ald)[node];
    int cntE = end - start;
    int mid = start + ((cntE + 1) >> 1);
    int k0 = half ? mid : start;
    int k1 = half ? end : mid;
    float acc[4][4] = {{0}};
    float s[4] = {0, 0, 0, 0};
    const ushort4* h04 = (const ushort4*)h0bf;
    for (int k = k0; k < k1; k += 4) {
        int e = k + g;
        if (e < k1) {
            int sn = csr[e];
            float4 av = ((const float4*)als)[sn];
            float e0 = av.x + adv.x; e0 = fmaxf(e0, 0.2f * e0);
            float e1 = av.y + adv.y; e1 = fmaxf(e1, 0.2f * e1);
            float e2 = av.z + adv.z; e2 = fmaxf(e2, 0.2f * e2);
            float e3 = av.w + adv.w; e3 = fmaxf(e3, 0.2f * e3);
            float w0 = __expf(e0), w1 = __expf(e1), w2 = __expf(e2), w3 = __expf(e3);
            s[0] += w0; s[1] += w1; s[2] += w2; s[3] += w3;
            ushort4 hv = h04[(size_t)sn * 16 + l16];
            float x0 = bf2f(hv.x), x1 = bf2f(hv.y), x2 = bf2f(hv.z), x3 = bf2f(hv.w);
            acc[0][0] += w0 * x0; acc[0][1] += w0 * x1; acc[0][2] += w0 * x2; acc[0][3] += w0 * x3;
            acc[1][0] += w1 * x0; acc[1][1] += w1 * x1; acc[1][2] += w1 * x2; acc[1][3] += w1 * x3;
            acc[2][0] += w2 * x0; acc[2][1] += w2 * x1; acc[2][2] += w2 * x2; acc[2][3] += w2 * x3;
            acc[3][0] += w3 * x0; acc[3][1] += w3 * x1; acc[3][2] += w3 * x2; acc[3][3] += w3 * x3;
        }
    }
    // combine the 4 edge-groups (lanes differing in bits 4..5)
#pragma unroll
    for (int h = 0; h < 4; h++) {
#pragma unroll
        for (int j = 0; j < 4; j++) {
            acc[h][j] += __shfl_xor(acc[h][j], 16, 64);
            acc[h][j] += __shfl_xor(acc[h][j], 32, 64);
        }
        s[h] += __shfl_xor(s[h], 16, 64);
        s[h] += __shfl_xor(s[h], 32, 64);
    }
    if (half) {
        float4 o = {acc[g][0], acc[g][1], acc[g][2], acc[g][3]};
        lacc[nloc][g * 16 + l16] = o;
        if (lane < 4) lss[nloc][lane] = s[lane];
    }
    __syncthreads();
    if (!half) {
#pragma unroll
        for (int h = 0; h < 4; h++) {
            float4 p = lacc[nloc][h * 16 + l16];
            acc[h][0] += p.x; acc[h][1] += p.y; acc[h][2] += p.z; acc[h][3] += p.w;
            s[h] += lss[nloc][h];
        }
        float inv = 1.0f / (s[g] + 1e-16f);
        ushort4 o = {f2bf(acc[g][0] * inv), f2bf(acc[g][1] * inv),
                     f2bf(acc[g][2] * inv), f2bf(acc[g][3] * inv)};
        ((ushort4*)aggbf)[(size_t)node * 64 + g * 16 + l16] = o;
    }
}

// ---------------- post-agg block-diagonal GEMM (64->256 per head) + bias + LN + GELU ----------------
__global__ void k_postgemm0(const unsigned short* __restrict__ A,
                            const unsigned short* __restrict__ Wpk,
                            const float* __restrict__ bias, const float* __restrict__ lng,
                            const float* __restrict__ lnb, unsigned short* __restrict__ h1bf) {
    int wid = threadIdx.x >> 6, lane = threadIdx.x & 63;
    int m0 = blockIdx.x * 64 + wid * 16;
    if (m0 >= N_NODES) return;
    int g16 = lane >> 4, c16 = lane & 15;
    f32x4 acc[16] = {};
#pragma unroll
    for (int h = 0; h < 4; h++) {
#pragma unroll
        for (int kt = 0; kt < 2; kt++) {
            bf16x8 a = *(const bf16x8*)(A + (size_t)(m0 + c16) * 256 + h * 64 + kt * 32 + g16 * 8);
#pragma unroll
            for (int nt = 0; nt < 4; nt++) {
                bf16x8 b = *(const bf16x8*)(Wpk + (((kt * 16 + h * 4 + nt) * 64 + lane) << 3));
                acc[h * 4 + nt] = __builtin_amdgcn_mfma_f32_16x16x32_bf16(a, b, acc[h * 4 + nt], 0, 0, 0);
            }
        }
    }
    float bv[16], gv[16], bb[16];
#pragma unroll
    for (int q = 0; q < 16; q++) {
        int c = q * 16 + c16;
        bv[q] = bias[c]; gv[q] = lng[c]; bb[q] = lnb[c];
    }
#pragma unroll
    for (int j = 0; j < 4; j++) {
        float d[16], ssum = 0.f;
#pragma unroll
        for (int q = 0; q < 16; q++) { d[q] = acc[q][j] + bv[q]; ssum += d[q]; }
        float mu = red16(ssum) * (1.0f / 256.0f);
        float v = 0.f;
#pragma unroll
        for (int q = 0; q < 16; q++) { d[q] -= mu; v += d[q] * d[q]; }
        float r = rsqrtf(red16(v) * (1.0f / 256.0f) + LN_EPS);
        int row = m0 + g16 * 4 + j;
#pragma unroll
        for (int q = 0; q < 16; q++) {
            float y = gelu_exact(d[q] * r * gv[q] + bb[q]);
            h1bf[(size_t)row * 256 + q * 16 + c16] = f2bf(y);
        }
    }
}

// ---------------- GAT projection (MFMA): xl(bf16) = A@W1 [N,256]->[N,256], + logits ----------------
__global__ void k_proj_mma(const unsigned short* __restrict__ A,
                           const unsigned short* __restrict__ Wpk,
                           const float* __restrict__ as_, const float* __restrict__ ad_,
                           unsigned short* __restrict__ xlbf, float* __restrict__ als,
                           float* __restrict__ ald) {
    int wid = threadIdx.x >> 6, lane = threadIdx.x & 63;  // wid = head
    int m0 = blockIdx.x * 16;
    int g16 = lane >> 4, c16 = lane & 15;
    f32x4 acc[4] = {{0,0,0,0},{0,0,0,0},{0,0,0,0},{0,0,0,0}};
#pragma unroll
    for (int kt = 0; kt < 8; kt++) {
        bf16x8 a = *(const bf16x8*)(A + (size_t)(m0 + c16) * 256 + kt * 32 + g16 * 8);
#pragma unroll
        for (int nt = 0; nt < 4; nt++) {
            bf16x8 b = *(const bf16x8*)(Wpk + (((kt * 16 + wid * 4 + nt) * 64 + lane) << 3));
            acc[nt] = __builtin_amdgcn_mfma_f32_16x16x32_bf16(a, b, acc[nt], 0, 0, 0);
        }
    }
    float asv[4], adv[4];
#pragma unroll
    for (int nt = 0; nt < 4; nt++) {
        int c = wid * 64 + nt * 16 + c16;
        asv[nt] = as_[c]; adv[nt] = ad_[c];
    }
#pragma unroll
    for (int j = 0; j < 4; j++) {
        int row = m0 + g16 * 4 + j;
        float ps = 0.f, pd = 0.f;
#pragma unroll
        for (int nt = 0; nt < 4; nt++) {
            float v = acc[nt][j];
            xlbf[(size_t)row * 256 + wid * 64 + nt * 16 + c16] = f2bf(v);
            ps += v * asv[nt]; pd += v * adv[nt];
        }
        ps = red16(ps); pd = red16(pd);
        if (c16 == 0) { als[row * 4 + wid] = ps; ald[row * 4 + wid] = pd; }
    }
}

// ---------------- layer-1 aggregation (512B/edge), single-pass, no max, fused epilogue ----------------
__global__ void k_agg1(const int* __restrict__ rowptr, const int* __restrict__ csr,
                       const unsigned short* __restrict__ xlbf, const float* __restrict__ als,
                       const float* __restrict__ ald, const float* __restrict__ bias,
                       const float* __restrict__ lng, const float* __restrict__ lnb,
                       const unsigned short* __restrict__ identity_bf,
                       const int* __restrict__ batch, float* __restrict__ pooled,
                       int* __restrict__ cnt) {
    __shared__ float4 lacc[2][64];
    __shared__ float lss[2][64];
    __shared__ float4 lyout[2][64];
    __shared__ int lbatch[2];
    int wid = threadIdx.x >> 6, lane = threadIdx.x & 63;
    int nloc = wid >> 1, half = wid & 1;
    int node = blockIdx.x * 2 + nloc;
    int start = rowptr[node], end = rowptr[node + 1];
    int head = lane >> 4;
    float adh = ald[node * 4 + head];
    int cntE = end - start;
    int mid = start + ((cntE + 1) >> 1);
    int k0 = half ? mid : start;
    int k1 = half ? end : mid;
    const ushort4* xl4 = (const ushort4*)xlbf;
    float4 acc = {0.f, 0.f, 0.f, 0.f};
    float s = 0.f;
    int k = k0;
    for (; k + 4 <= k1; k += 4) {
        int sn0 = csr[k], sn1 = csr[k + 1], sn2 = csr[k + 2], sn3 = csr[k + 3];
        float e0 = als[sn0 * 4 + head] + adh;
        float e1 = als[sn1 * 4 + head] + adh;
        float e2 = als[sn2 * 4 + head] + adh;
        float e3 = als[sn3 * 4 + head] + adh;
        ushort4 v0 = xl4[(size_t)sn0 * 64 + lane];
        ushort4 v1 = xl4[(size_t)sn1 * 64 + lane];
        ushort4 v2 = xl4[(size_t)sn2 * 64 + lane];
        ushort4 v3 = xl4[(size_t)sn3 * 64 + lane];
        e0 = fmaxf(e0, 0.2f * e0); e1 = fmaxf(e1, 0.2f * e1);
        e2 = fmaxf(e2, 0.2f * e2); e3 = fmaxf(e3, 0.2f * e3);
        float a0 = __expf(e0), a1 = __expf(e1), a2 = __expf(e2), a3 = __expf(e3);
        s += a0 + a1 + a2 + a3;
        acc.x += a0 * bf2f(v0.x) + a1 * bf2f(v1.x) + a2 * bf2f(v2.x) + a3 * bf2f(v3.x);
        acc.y += a0 * bf2f(v0.y) + a1 * bf2f(v1.y) + a2 * bf2f(v2.y) + a3 * bf2f(v3.y);
        acc.z += a0 * bf2f(v0.z) + a1 * bf2f(v1.z) + a2 * bf2f(v2.z) + a3 * bf2f(v3.z);
        acc.w += a0 * bf2f(v0.w) + a1 * bf2f(v1.w) + a2 * bf2f(v2.w) + a3 * bf2f(v3.w);
    }
    for (; k < k1; k++) {
        int sn = csr[k];
        float e = als[sn * 4 + head] + adh;
        e = fmaxf(e, 0.2f * e);
        float a = __expf(e);
        s += a;
        ushort4 v = xl4[(size_t)sn * 64 + lane];
        acc.x += a * bf2f(v.x); acc.y += a * bf2f(v.y);
        acc.z += a * bf2f(v.z); acc.w += a * bf2f(v.w);
    }
    if (half) { lacc[nloc][lane] = acc; lss[nloc][lane] = s; }
    __syncthreads();
    if (!half) {
        float4 p = lacc[nloc][lane];
        acc.x += p.x; acc.y += p.y; acc.z += p.z; acc.w += p.w;
        s += lss[nloc][lane];
        float inv = 1.0f / (s + 1e-16f);
        acc.x *= inv; acc.y *= inv; acc.z *= inv; acc.w *= inv;
        float4 bv = ((const float4*)bias)[lane];
        acc.x += bv.x; acc.y += bv.y; acc.z += bv.z; acc.w += bv.w;
        float mu = wave_sum(acc.x + acc.y + acc.z + acc.w) * (1.0f / 256.0f);
        float dx = acc.x - mu, dy = acc.y - mu, dz = acc.z - mu, dw = acc.w - mu;
        float var = wave_sum(dx * dx + dy * dy + dz * dz + dw * dw) * (1.0f / 256.0f);
        float r = rsqrtf(var + LN_EPS);
        float4 gv = ((const float4*)lng)[lane];
        float4 bb = ((const float4*)lnb)[lane];
        ushort4 idv = ((const ushort4*)identity_bf)[(size_t)node * 64 + lane];
        float4 y;
        y.x = gelu_exact(dx * r * gv.x + bb.x) + bf2f(idv.x);
        y.y = gelu_exact(dy * r * gv.y + bb.y) + bf2f(idv.y);
        y.z = gelu_exact(dz * r * gv.z + bb.z) + bf2f(idv.z);
        y.w = gelu_exact(dw * r * gv.w + bb.w) + bf2f(idv.w);
        lyout[nloc][lane] = y;
        if (lane == 0) lbatch[nloc] = batch[node];
    }
    __syncthreads();
    if (wid == 0) {
        int g0 = lbatch[0], g1 = lbatch[1];
        float4 a = lyout[0][lane], b = lyout[1][lane];
        float* p0 = pooled + (size_t)g0 * 256 + 4 * lane;
        if (g0 == g1) {
            atomicAdd(p0 + 0, a.x + b.x); atomicAdd(p0 + 1, a.y + b.y);
            atomicAdd(p0 + 2, a.z + b.z); atomicAdd(p0 + 3, a.w + b.w);
            if (lane == 0) atomicAdd(cnt + g0, 2);
        } else {
            float* p1 = pooled + (size_t)g1 * 256 + 4 * lane;
            atomicAdd(p0 + 0, a.x); atomicAdd(p0 + 1, a.y);
            atomicAdd(p0 + 2, a.z); atomicAdd(p0 + 3, a.w);
            atomicAdd(p1 + 0, b.x); atomicAdd(p1 + 1, b.y);
            atomicAdd(p1 + 2, b.z); atomicAdd(p1 + 3, b.w);
            if (lane == 0) { atomicAdd(cnt + g0, 1); atomicAdd(cnt + g1, 1); }
        }
    }
}

// ---------------- pooled MLP + log_softmax: one wave per graph ----------------
__global__ void k_final(const float* __restrict__ pooled, const int* __restrict__ cnt,
                        const float* __restrict__ fc1W, const float* __restrict__ fc1b,
                        const float* __restrict__ fc2W, const float* __restrict__ fc2b,
                        float* __restrict__ out) {
    __shared__ float prow[4][256];
    __shared__ float zrow[4][64];
    int wid = threadIdx.x >> 6, lane = threadIdx.x & 63;
    int g = blockIdx.x * 4 + wid;
    float inv = 1.0f / fmaxf((float)cnt[g], 1.0f);
#pragma unroll
    for (int k = lane; k < 256; k += 64) prow[wid][k] = pooled[g * 256 + k] * inv;
    __syncthreads();
    float acc = fc1b[lane];
#pragma unroll 4
    for (int k = 0; k < 256; k++) acc += prow[wid][k] * fc1W[k * 64 + lane];
    zrow[wid][lane] = gelu_exact(acc);
    __syncthreads();
    float logit = fc2b[lane];
#pragma unroll 4
    for (int k = 0; k < 64; k++) logit += zrow[wid][k] * fc2W[k * 64 + lane];
    float mx = wave_max(logit);
    float se = wave_sum(__expf(logit - mx));
    out[g * NOUT + lane] = logit - mx - logf(se);
}

extern "C" void kernel_launch(void* const* d_in, const int* in_sizes, int n_in,
                              void* d_out, int out_size, void* d_ws, size_t ws_size,
                              hipStream_t stream) {
    const float* x     = (const float*)d_in[0];
    const int*   ei    = (const int*)d_in[1];
    const int*   batch = (const int*)d_in[2];
    const int*   gid   = (const int*)d_in[3];
    const float* gt    = (const float*)d_in[4];
    const float* inW   = (const float*)d_in[5];
    const float* inb   = (const float*)d_in[6];
    const float* inlng = (const float*)d_in[7];
    const float* inlnb = (const float*)d_in[8];
    const float* W0    = (const float*)d_in[9];
    const float* as0   = (const float*)d_in[10];
    const float* ad0   = (const float*)d_in[11];
    const float* b0    = (const float*)d_in[12];
    const float* ln0g  = (const float*)d_in[13];
    const float* ln0b  = (const float*)d_in[14];
    const float* W1    = (const float*)d_in[15];
    const float* as1   = (const float*)d_in[16];
    const float* ad1   = (const float*)d_in[17];
    const float* b1    = (const float*)d_in[18];
    const float* ln1g  = (const float*)d_in[19];
    const float* ln1b  = (const float*)d_in[20];
    const float* fc1W  = (const float*)d_in[21];
    const float* fc1b  = (const float*)d_in[22];
    const float* fc2W  = (const float*)d_in[23];
    const float* fc2b  = (const float*)d_in[24];
    float* out = (float*)d_out;

    char* ws = (char*)d_ws;
    size_t off = 0;
    auto alloc = [&](size_t bytes) {
        void* p = ws + off;
        off += (bytes + 255) / 256 * 256;
        return p;
    };
    unsigned short* Ain    = (unsigned short*)alloc((size_t)N_NODES * 192 * 2);
    unsigned short* h0bf   = (unsigned short*)alloc((size_t)N_NODES * 64 * 2);
    unsigned short* agg0bf = (unsigned short*)alloc((size_t)N_NODES * 256 * 2);
    unsigned short* h1bf   = (unsigned short*)alloc((size_t)N_NODES * 256 * 2);
    unsigned short* xlbf   = (unsigned short*)alloc((size_t)N_NODES * 256 * 2);
    unsigned short* inWpk  = (unsigned short*)alloc((size_t)192 * 64 * 2);
    unsigned short* W0pk   = (unsigned short*)alloc((size_t)64 * 256 * 2);
    unsigned short* W1pk   = (unsigned short*)alloc((size_t)256 * 256 * 2);
    float* us     = (float*)alloc((size_t)256 * 4);
    float* ud     = (float*)alloc((size_t)256 * 4);
    float* als0   = (float*)alloc((size_t)N_NODES * 4 * 4);
    float* ald0   = (float*)alloc((size_t)N_NODES * 4 * 4);
    float* als1   = (float*)alloc((size_t)N_NODES * 4 * 4);
    float* ald1   = (float*)alloc((size_t)N_NODES * 4 * 4);
    int*   rowptr = (int*)alloc((size_t)(N_NODES + 1) * 4);
    int*   cursor = (int*)alloc((size_t)N_NODES * 4);
    int*   csr    = (int*)alloc((size_t)ETOT * 4);
    int*   deg    = (int*)alloc((size_t)N_NODES * 4);
    float* pooled = (float*)alloc((size_t)NGRAPH * 256 * 4);
    int*   cnt    = (int*)alloc((size_t)NGRAPH * 4);

    hipMemsetAsync(deg, 0, (size_t)N_NODES * 4, stream);
    hipMemsetAsync(pooled, 0, (size_t)NGRAPH * 256 * 4, stream);
    hipMemsetAsync(cnt, 0, (size_t)NGRAPH * 4, stream);

    int eb = (ETOT + 255) / 256;
    k_count<<<eb, 256, 0, stream>>>(ei, deg);
    k_scan<<<1, 1024, 0, stream>>>(deg, rowptr, cursor);
    k_fill<<<eb, 256, 0, stream>>>(ei, cursor, csr);

    k_prep<<<N_NODES / 4, 256, 0, stream>>>(x, gid, gt, Ain);
    k_pack<<<(192 * 64 + 255) / 256, 256, 0, stream>>>(inW, inWpk, 192, 64);
    k_pack<<<(64 * 256 + 255) / 256, 256, 0, stream>>>(W0, W0pk, 64, 256);
    k_pack<<<(256 * 256 + 255) / 256, 256, 0, stream>>>(W1, W1pk, 256, 256);
    k_prep_u<<<1, 256, 0, stream>>>(W0, as0, ad0, us, ud);

    k_proj_in_mma<<<(N_NODES + 63) / 64, 256, 0, stream>>>(Ain, inWpk, inb, inlng, inlnb, h0bf);
    k_logits<<<N_NODES / 16, 256, 0, stream>>>(h0bf, us, ud, als0, ald0);
    k_agg0<<<N_NODES / 2, 256, 0, stream>>>(rowptr, csr, h0bf, als0, ald0, agg0bf);
    k_postgemm0<<<(N_NODES + 63) / 64, 256, 0, stream>>>(agg0bf, W0pk, b0, ln0g, ln0b, h1bf);
    k_proj_mma<<<N_NODES / 16, 256, 0, stream>>>(h1bf, W1pk, as1, ad1, xlbf, als1, ald1);
    k_agg1<<<N_NODES / 2, 256, 0, stream>>>(rowptr, csr, xlbf, als1, ald1, b1, ln1g, ln1b,
                                            h1bf, batch, pooled, cnt);
    k_final<<<NGRAPH / 4, 256, 0, stream>>>(pooled, cnt, fc1W, fc1b, fc2W, fc2b, out);
}

// Round 6
// 478.786 us; speedup vs baseline: 1.3810x; 1.3810x over previous
//
#include <hip/hip_runtime.h>
#include <math.h>

#define N_NODES 50000
#define N_EDGES 800000
#define ETOT (N_EDGES + N_NODES)
#define F_IN 128
#define HD 64
#define NHEAD 4
#define HC 256
#define NGRAPH 512
#define NOUT 64
#define LN_EPS 1e-5f

typedef __attribute__((ext_vector_type(8))) short bf16x8;
typedef __attribute__((ext_vector_type(4))) float f32x4;

__device__ __forceinline__ float wave_sum(float v) {
#pragma unroll
    for (int m = 1; m < 64; m <<= 1) v += __shfl_xor(v, m, 64);
    return v;
}
__device__ __forceinline__ float wave_max(float v) {
#pragma unroll
    for (int m = 1; m < 64; m <<= 1) v = fmaxf(v, __shfl_xor(v, m, 64));
    return v;
}
__device__ __forceinline__ float red16(float v) {
    v += __shfl_xor(v, 1, 64);
    v += __shfl_xor(v, 2, 64);
    v += __shfl_xor(v, 4, 64);
    v += __shfl_xor(v, 8, 64);
    return v;
}
__device__ __forceinline__ float gelu_exact(float x) {
    return 0.5f * x * (1.0f + erff(x * 0.70710678118654752f));
}
__device__ __forceinline__ unsigned short f2bf(float x) {
    unsigned int u = __float_as_uint(x);
    return (unsigned short)((u + 0x7fffu + ((u >> 16) & 1u)) >> 16);
}
__device__ __forceinline__ float bf2f(unsigned short u) {
    return __uint_as_float(((unsigned int)u) << 16);
}

// ---------------- CSR build ----------------
__global__ void k_count(const int* __restrict__ ei, int* __restrict__ deg) {
    int t = blockIdx.x * blockDim.x + threadIdx.x;
    if (t >= ETOT) return;
    int dst = (t < N_EDGES) ? ei[N_EDGES + t] : (t - N_EDGES);
    atomicAdd(deg + dst, 1);
}

__global__ void k_scan(const int* __restrict__ deg, int* __restrict__ rowptr,
                       int* __restrict__ cursor) {
    __shared__ int wsum[16];
    __shared__ int chunk_total;
    int tid = threadIdx.x, wid = tid >> 6, lane = tid & 63;
    int carry = 0;
    if (tid == 0) rowptr[0] = 0;
    for (int base = 0; base < N_NODES; base += 1024) {
        int i = base + tid;
        int v = (i < N_NODES) ? deg[i] : 0;
        int incl = v;
#pragma unroll
        for (int off = 1; off < 64; off <<= 1) {
            int t = __shfl_up(incl, off, 64);
            if (lane >= off) incl += t;
        }
        if (lane == 63) wsum[wid] = incl;
        __syncthreads();
        if (wid == 0) {
            int wv = (lane < 16) ? wsum[lane] : 0;
            int wincl = wv;
#pragma unroll
            for (int off = 1; off < 16; off <<= 1) {
                int t = __shfl_up(wincl, off, 64);
                if (lane >= off) wincl += t;
            }
            if (lane < 16) wsum[lane] = wincl - wv;
            if (lane == 15) chunk_total = wincl;
        }
        __syncthreads();
        int total_incl = carry + wsum[wid] + incl;
        if (i < N_NODES) {
            rowptr[i + 1] = total_incl;
            cursor[i] = total_incl - v;
        }
        carry += chunk_total;
        __syncthreads();
    }
}

__global__ void k_fill(const int* __restrict__ ei, int* __restrict__ cursor,
                       int* __restrict__ csr) {
    int t = blockIdx.x * blockDim.x + threadIdx.x;
    if (t >= ETOT) return;
    int src, dst;
    if (t < N_EDGES) { src = ei[t]; dst = ei[N_EDGES + t]; }
    else             { src = t - N_EDGES; dst = src; }
    int p = atomicAdd(cursor + dst, 1);
    csr[p] = src;
}

// ---------------- prep: concat(x, group_emb) -> bf16 [N, 192] ----------------
__global__ void k_prep(const float* __restrict__ x, const int* __restrict__ gid,
                       const float* __restrict__ gt, unsigned short* __restrict__ Ain) {
    int wid = threadIdx.x >> 6, lane = threadIdx.x & 63;
    int node = blockIdx.x * 4 + wid;
    float f0 = x[node * F_IN + lane];
    float f1 = x[node * F_IN + 64 + lane];
    int g = gid[node];
    float f2 = gt[g * HD + lane];
    unsigned short* r = Ain + (size_t)node * 192;
    r[lane] = f2bf(f0);
    r[64 + lane] = f2bf(f1);
    r[128 + lane] = f2bf(f2);
}

// ---------------- pack W [K,N] f32 -> fragment-order bf16 [K/32][N/16][64][8] ----------------
__global__ void k_pack(const float* __restrict__ W, unsigned short* __restrict__ out,
                       int K, int N) {
    int tid = blockIdx.x * blockDim.x + threadIdx.x;
    int NB = N >> 4;
    int total = (K >> 5) * NB * 512;
    if (tid >= total) return;
    int i = tid & 7;
    int l = (tid >> 3) & 63;
    int t2 = tid >> 9;
    int nb = t2 % NB;
    int kt = t2 / NB;
    int k = kt * 32 + ((l >> 4) << 3) + i;
    int n = nb * 16 + (l & 15);
    out[tid] = f2bf(W[k * N + n]);
}

// ---------------- u vectors: u_s[h][k] = sum_c W0[k, h*64+c] * a[h][c] ----------------
__global__ void k_prep_u(const float* __restrict__ W0, const float* __restrict__ as_,
                         const float* __restrict__ ad_, float* __restrict__ us,
                         float* __restrict__ ud) {
    int t = threadIdx.x;
    int h = t >> 6, k = t & 63;
    float ss = 0.f, dd = 0.f;
    for (int c = 0; c < 64; c++) {
        float w = W0[k * 256 + h * 64 + c];
        ss += w * as_[h * 64 + c];
        dd += w * ad_[h * 64 + c];
    }
    us[t] = ss;
    ud[t] = dd;
}

// ---------------- input projection (MFMA): [N,192]@[192,64] -> LN -> GELU -> bf16 ----------------
__global__ void k_proj_in_mma(const unsigned short* __restrict__ A,
                              const unsigned short* __restrict__ Wpk,
                              const float* __restrict__ inb, const float* __restrict__ lng,
                              const float* __restrict__ lnb, unsigned short* __restrict__ h0bf) {
    int wid = threadIdx.x >> 6, lane = threadIdx.x & 63;
    int m0 = blockIdx.x * 64 + wid * 16;
    if (m0 >= N_NODES) return;
    int g16 = lane >> 4, c16 = lane & 15;
    f32x4 acc[4] = {{0,0,0,0},{0,0,0,0},{0,0,0,0},{0,0,0,0}};
#pragma unroll
    for (int kt = 0; kt < 6; kt++) {
        bf16x8 a = *(const bf16x8*)(A + (size_t)(m0 + c16) * 192 + kt * 32 + g16 * 8);
#pragma unroll
        for (int nt = 0; nt < 4; nt++) {
            bf16x8 b = *(const bf16x8*)(Wpk + (((kt * 4 + nt) * 64 + lane) << 3));
            acc[nt] = __builtin_amdgcn_mfma_f32_16x16x32_bf16(a, b, acc[nt], 0, 0, 0);
        }
    }
    float bv[4], gv[4], bb[4];
#pragma unroll
    for (int nt = 0; nt < 4; nt++) {
        int c = nt * 16 + c16;
        bv[nt] = inb[c]; gv[nt] = lng[c]; bb[nt] = lnb[c];
    }
#pragma unroll
    for (int j = 0; j < 4; j++) {
        float d[4], s = 0.f;
#pragma unroll
        for (int nt = 0; nt < 4; nt++) { d[nt] = acc[nt][j] + bv[nt]; s += d[nt]; }
        float mu = red16(s) * (1.0f / 64.0f);
        float v = 0.f;
#pragma unroll
        for (int nt = 0; nt < 4; nt++) { d[nt] -= mu; v += d[nt] * d[nt]; }
        float r = rsqrtf(red16(v) * (1.0f / 64.0f) + LN_EPS);
        int row = m0 + g16 * 4 + j;
#pragma unroll
        for (int nt = 0; nt < 4; nt++) {
            float y = gelu_exact(d[nt] * r * gv[nt] + bb[nt]);
            h0bf[(size_t)row * 64 + nt * 16 + c16] = f2bf(y);
        }
    }
}

// ---------------- layer-0 logits: als[n,h] = h0[n,:]·u_s[h,:] ----------------
__global__ void k_logits(const unsigned short* __restrict__ h0bf, const float* __restrict__ us,
                         const float* __restrict__ ud, float* __restrict__ als,
                         float* __restrict__ ald) {
    int wid = threadIdx.x >> 6, lane = threadIdx.x & 63;
    int g = lane >> 4, l16 = lane & 15;
    int node = blockIdx.x * 16 + wid * 4 + g;
    ushort4 hv = ((const ushort4*)h0bf)[(size_t)node * 16 + l16];
    float v0 = bf2f(hv.x), v1 = bf2f(hv.y), v2 = bf2f(hv.z), v3 = bf2f(hv.w);
#pragma unroll
    for (int h = 0; h < 4; h++) {
        const float* u = us + h * 64 + 4 * l16;
        const float* w = ud + h * 64 + 4 * l16;
        float ps = v0 * u[0] + v1 * u[1] + v2 * u[2] + v3 * u[3];
        float pd = v0 * w[0] + v1 * w[1] + v2 * w[2] + v3 * w[3];
        ps = red16(ps); pd = red16(pd);
        if (l16 == 0) { als[node * 4 + h] = ps; ald[node * 4 + h] = pd; }
    }
}

// ---------------- layer-0 aggregation over h0 (128B/edge), single-pass, no max ----------------
// Named scalar accumulators everywhere (NO runtime-indexed private arrays -> no LDS promotion).
__global__ void k_agg0(const int* __restrict__ rowptr, const int* __restrict__ csr,
                       const unsigned short* __restrict__ h0bf, const float* __restrict__ als,
                       const float* __restrict__ ald, unsigned short* __restrict__ aggbf) {
    __shared__ float4 lacc[2][64];
    __shared__ float lss[2][4];
    int wid = threadIdx.x >> 6, lane = threadIdx.x & 63;
    int nloc = wid >> 1, half = wid & 1;
    int node = blockIdx.x * 2 + nloc;
    int start = rowptr[node], end = rowptr[node + 1];
    int g = lane >> 4, l16 = lane & 15;
    float4 adv = ((const float4*)ald)[node];
    int cntE = end - start;
    int mid = start + ((cntE + 1) >> 1);
    int k0 = half ? mid : start;
    int k1 = half ? end : mid;
    float a00 = 0, a01 = 0, a02 = 0, a03 = 0;
    float a10 = 0, a11 = 0, a12 = 0, a13 = 0;
    float a20 = 0, a21 = 0, a22 = 0, a23 = 0;
    float a30 = 0, a31 = 0, a32 = 0, a33 = 0;
    float s0 = 0, s1 = 0, s2 = 0, s3 = 0;
    const ushort4* h04 = (const ushort4*)h0bf;
    for (int kb = k0; kb < k1; kb += 4) {
        int e = kb + g;
        if (e < k1) {
            int sn = csr[e];
            float4 av = ((const float4*)als)[sn];
            float e0 = av.x + adv.x; e0 = fmaxf(e0, 0.2f * e0);
            float e1 = av.y + adv.y; e1 = fmaxf(e1, 0.2f * e1);
            float e2 = av.z + adv.z; e2 = fmaxf(e2, 0.2f * e2);
            float e3 = av.w + adv.w; e3 = fmaxf(e3, 0.2f * e3);
            float w0 = __expf(e0), w1 = __expf(e1), w2 = __expf(e2), w3 = __expf(e3);
            s0 += w0; s1 += w1; s2 += w2; s3 += w3;
            ushort4 hv = h04[(size_t)sn * 16 + l16];
            float x0 = bf2f(hv.x), x1 = bf2f(hv.y), x2 = bf2f(hv.z), x3 = bf2f(hv.w);
            a00 += w0 * x0; a01 += w0 * x1; a02 += w0 * x2; a03 += w0 * x3;
            a10 += w1 * x0; a11 += w1 * x1; a12 += w1 * x2; a13 += w1 * x3;
            a20 += w2 * x0; a21 += w2 * x1; a22 += w2 * x2; a23 += w2 * x3;
            a30 += w3 * x0; a31 += w3 * x1; a32 += w3 * x2; a33 += w3 * x3;
        }
    }
    // reduce across the 4 edge-groups (lane bits 4..5)
#define RED2(v) v += __shfl_xor(v, 16, 64); v += __shfl_xor(v, 32, 64)
    RED2(a00); RED2(a01); RED2(a02); RED2(a03);
    RED2(a10); RED2(a11); RED2(a12); RED2(a13);
    RED2(a20); RED2(a21); RED2(a22); RED2(a23);
    RED2(a30); RED2(a31); RED2(a32); RED2(a33);
    RED2(s0);  RED2(s1);  RED2(s2);  RED2(s3);
#undef RED2
    if (half) {
        float o0 = (g == 0) ? a00 : (g == 1) ? a10 : (g == 2) ? a20 : a30;
        float o1 = (g == 0) ? a01 : (g == 1) ? a11 : (g == 2) ? a21 : a31;
        float o2 = (g == 0) ? a02 : (g == 1) ? a12 : (g == 2) ? a22 : a32;
        float o3 = (g == 0) ? a03 : (g == 1) ? a13 : (g == 2) ? a23 : a33;
        float4 o = {o0, o1, o2, o3};
        lacc[nloc][lane] = o;
        if (lane < 4) {
            float sv = (lane == 0) ? s0 : (lane == 1) ? s1 : (lane == 2) ? s2 : s3;
            lss[nloc][lane] = sv;
        }
    }
    __syncthreads();
    if (!half) {
        float4 p0 = lacc[nloc][0 + l16];
        float4 p1 = lacc[nloc][16 + l16];
        float4 p2 = lacc[nloc][32 + l16];
        float4 p3 = lacc[nloc][48 + l16];
        a00 += p0.x; a01 += p0.y; a02 += p0.z; a03 += p0.w;
        a10 += p1.x; a11 += p1.y; a12 += p1.z; a13 += p1.w;
        a20 += p2.x; a21 += p2.y; a22 += p2.z; a23 += p2.w;
        a30 += p3.x; a31 += p3.y; a32 += p3.z; a33 += p3.w;
        s0 += lss[nloc][0]; s1 += lss[nloc][1];
        s2 += lss[nloc][2]; s3 += lss[nloc][3];
        float o0 = (g == 0) ? a00 : (g == 1) ? a10 : (g == 2) ? a20 : a30;
        float o1 = (g == 0) ? a01 : (g == 1) ? a11 : (g == 2) ? a21 : a31;
        float o2 = (g == 0) ? a02 : (g == 1) ? a12 : (g == 2) ? a22 : a32;
        float o3 = (g == 0) ? a03 : (g == 1) ? a13 : (g == 2) ? a23 : a33;
        float sg = (g == 0) ? s0 : (g == 1) ? s1 : (g == 2) ? s2 : s3;
        float inv = 1.0f / (sg + 1e-16f);
        ushort4 o = {f2bf(o0 * inv), f2bf(o1 * inv), f2bf(o2 * inv), f2bf(o3 * inv)};
        ((ushort4*)aggbf)[(size_t)node * 64 + lane] = o;
    }
}

// ---------------- post-agg block-diagonal GEMM (64->256 per head) + bias + LN + GELU ----------------
__global__ void k_postgemm0(const unsigned short* __restrict__ A,
                            const unsigned short* __restrict__ Wpk,
                            const float* __restrict__ bias, const float* __restrict__ lng,
                            const float* __restrict__ lnb, unsigned short* __restrict__ h1bf) {
    int wid = threadIdx.x >> 6, lane = threadIdx.x & 63;
    int m0 = blockIdx.x * 64 + wid * 16;
    if (m0 >= N_NODES) return;
    int g16 = lane >> 4, c16 = lane & 15;
    f32x4 acc[16] = {};
#pragma unroll
    for (int h = 0; h < 4; h++) {
#pragma unroll
        for (int kt = 0; kt < 2; kt++) {
            bf16x8 a = *(const bf16x8*)(A + (size_t)(m0 + c16) * 256 + h * 64 + kt * 32 + g16 * 8);
#pragma unroll
            for (int nt = 0; nt < 4; nt++) {
                bf16x8 b = *(const bf16x8*)(Wpk + (((kt * 16 + h * 4 + nt) * 64 + lane) << 3));
                acc[h * 4 + nt] = __builtin_amdgcn_mfma_f32_16x16x32_bf16(a, b, acc[h * 4 + nt], 0, 0, 0);
            }
        }
    }
    float bv[16], gv[16], bb[16];
#pragma unroll
    for (int q = 0; q < 16; q++) {
        int c = q * 16 + c16;
        bv[q] = bias[c]; gv[q] = lng[c]; bb[q] = lnb[c];
    }
#pragma unroll
    for (int j = 0; j < 4; j++) {
        float d[16], ssum = 0.f;
#pragma unroll
        for (int q = 0; q < 16; q++) { d[q] = acc[q][j] + bv[q]; ssum += d[q]; }
        float mu = red16(ssum) * (1.0f / 256.0f);
        float v = 0.f;
#pragma unroll
        for (int q = 0; q < 16; q++) { d[q] -= mu; v += d[q] * d[q]; }
        float r = rsqrtf(red16(v) * (1.0f / 256.0f) + LN_EPS);
        int row = m0 + g16 * 4 + j;
#pragma unroll
        for (int q = 0; q < 16; q++) {
            float y = gelu_exact(d[q] * r * gv[q] + bb[q]);
            h1bf[(size_t)row * 256 + q * 16 + c16] = f2bf(y);
        }
    }
}

// ---------------- GAT projection (MFMA): xl(bf16) = A@W1 [N,256]->[N,256], + logits ----------------
__global__ void k_proj_mma(const unsigned short* __restrict__ A,
                           const unsigned short* __restrict__ Wpk,
                           const float* __restrict__ as_, const float* __restrict__ ad_,
                           unsigned short* __restrict__ xlbf, float* __restrict__ als,
                           float* __restrict__ ald) {
    int wid = threadIdx.x >> 6, lane = threadIdx.x & 63;  // wid = head
    int m0 = blockIdx.x * 16;
    int g16 = lane >> 4, c16 = lane & 15;
    f32x4 acc[4] = {{0,0,0,0},{0,0,0,0},{0,0,0,0},{0,0,0,0}};
#pragma unroll
    for (int kt = 0; kt < 8; kt++) {
        bf16x8 a = *(const bf16x8*)(A + (size_t)(m0 + c16) * 256 + kt * 32 + g16 * 8);
#pragma unroll
        for (int nt = 0; nt < 4; nt++) {
            bf16x8 b = *(const bf16x8*)(Wpk + (((kt * 16 + wid * 4 + nt) * 64 + lane) << 3));
            acc[nt] = __builtin_amdgcn_mfma_f32_16x16x32_bf16(a, b, acc[nt], 0, 0, 0);
        }
    }
    float asv[4], adv[4];
#pragma unroll
    for (int nt = 0; nt < 4; nt++) {
        int c = wid * 64 + nt * 16 + c16;
        asv[nt] = as_[c]; adv[nt] = ad_[c];
    }
#pragma unroll
    for (int j = 0; j < 4; j++) {
        int row = m0 + g16 * 4 + j;
        float ps = 0.f, pd = 0.f;
#pragma unroll
        for (int nt = 0; nt < 4; nt++) {
            float v = acc[nt][j];
            xlbf[(size_t)row * 256 + wid * 64 + nt * 16 + c16] = f2bf(v);
            ps += v * asv[nt]; pd += v * adv[nt];
        }
        ps = red16(ps); pd = red16(pd);
        if (c16 == 0) { als[row * 4 + wid] = ps; ald[row * 4 + wid] = pd; }
    }
}

// ---------------- layer-1 aggregation (512B/edge), single-pass, no max, fused epilogue ----------------
__global__ void k_agg1(const int* __restrict__ rowptr, const int* __restrict__ csr,
                       const unsigned short* __restrict__ xlbf, const float* __restrict__ als,
                       const float* __restrict__ ald, const float* __restrict__ bias,
                       const float* __restrict__ lng, const float* __restrict__ lnb,
                       const unsigned short* __restrict__ identity_bf,
                       const int* __restrict__ batch, float* __restrict__ pooled,
                       int* __restrict__ cnt) {
    __shared__ float4 lacc[2][64];
    __shared__ float lss[2][64];
    __shared__ float4 lyout[2][64];
    __shared__ int lbatch[2];
    int wid = threadIdx.x >> 6, lane = threadIdx.x & 63;
    int nloc = wid >> 1, half = wid & 1;
    int node = blockIdx.x * 2 + nloc;
    int start = rowptr[node], end = rowptr[node + 1];
    int head = lane >> 4;
    float adh = ald[node * 4 + head];
    int cntE = end - start;
    int mid = start + ((cntE + 1) >> 1);
    int k0 = half ? mid : start;
    int k1 = half ? end : mid;
    const ushort4* xl4 = (const ushort4*)xlbf;
    float4 acc = {0.f, 0.f, 0.f, 0.f};
    float s = 0.f;
    int k = k0;
    for (; k + 4 <= k1; k += 4) {
        int sn0 = csr[k], sn1 = csr[k + 1], sn2 = csr[k + 2], sn3 = csr[k + 3];
        float e0 = als[sn0 * 4 + head] + adh;
        float e1 = als[sn1 * 4 + head] + adh;
        float e2 = als[sn2 * 4 + head] + adh;
        float e3 = als[sn3 * 4 + head] + adh;
        ushort4 v0 = xl4[(size_t)sn0 * 64 + lane];
        ushort4 v1 = xl4[(size_t)sn1 * 64 + lane];
        ushort4 v2 = xl4[(size_t)sn2 * 64 + lane];
        ushort4 v3 = xl4[(size_t)sn3 * 64 + lane];
        e0 = fmaxf(e0, 0.2f * e0); e1 = fmaxf(e1, 0.2f * e1);
        e2 = fmaxf(e2, 0.2f * e2); e3 = fmaxf(e3, 0.2f * e3);
        float a0 = __expf(e0), a1 = __expf(e1), a2 = __expf(e2), a3 = __expf(e3);
        s += a0 + a1 + a2 + a3;
        acc.x += a0 * bf2f(v0.x) + a1 * bf2f(v1.x) + a2 * bf2f(v2.x) + a3 * bf2f(v3.x);
        acc.y += a0 * bf2f(v0.y) + a1 * bf2f(v1.y) + a2 * bf2f(v2.y) + a3 * bf2f(v3.y);
        acc.z += a0 * bf2f(v0.z) + a1 * bf2f(v1.z) + a2 * bf2f(v2.z) + a3 * bf2f(v3.z);
        acc.w += a0 * bf2f(v0.w) + a1 * bf2f(v1.w) + a2 * bf2f(v2.w) + a3 * bf2f(v3.w);
    }
    for (; k < k1; k++) {
        int sn = csr[k];
        float e = als[sn * 4 + head] + adh;
        e = fmaxf(e, 0.2f * e);
        float a = __expf(e);
        s += a;
        ushort4 v = xl4[(size_t)sn * 64 + lane];
        acc.x += a * bf2f(v.x); acc.y += a * bf2f(v.y);
        acc.z += a * bf2f(v.z); acc.w += a * bf2f(v.w);
    }
    if (half) { lacc[nloc][lane] = acc; lss[nloc][lane] = s; }
    __syncthreads();
    if (!half) {
        float4 p = lacc[nloc][lane];
        acc.x += p.x; acc.y += p.y; acc.z += p.z; acc.w += p.w;
        s += lss[nloc][lane];
        float inv = 1.0f / (s + 1e-16f);
        acc.x *= inv; acc.y *= inv; acc.z *= inv; acc.w *= inv;
        float4 bv = ((const float4*)bias)[lane];
        acc.x += bv.x; acc.y += bv.y; acc.z += bv.z; acc.w += bv.w;
        float mu = wave_sum(acc.x + acc.y + acc.z + acc.w) * (1.0f / 256.0f);
        float dx = acc.x - mu, dy = acc.y - mu, dz = acc.z - mu, dw = acc.w - mu;
        float var = wave_sum(dx * dx + dy * dy + dz * dz + dw * dw) * (1.0f / 256.0f);
        float r = rsqrtf(var + LN_EPS);
        float4 gv = ((const float4*)lng)[lane];
        float4 bb = ((const float4*)lnb)[lane];
        ushort4 idv = ((const ushort4*)identity_bf)[(size_t)node * 64 + lane];
        float4 y;
        y.x = gelu_exact(dx * r * gv.x + bb.x) + bf2f(idv.x);
        y.y = gelu_exact(dy * r * gv.y + bb.y) + bf2f(idv.y);
        y.z = gelu_exact(dz * r * gv.z + bb.z) + bf2f(idv.z);
        y.w = gelu_exact(dw * r * gv.w + bb.w) + bf2f(idv.w);
        lyout[nloc][lane] = y;
        if (lane == 0) lbatch[nloc] = batch[node];
    }
    __syncthreads();
    if (wid == 0) {
        int g0 = lbatch[0], g1 = lbatch[1];
        float4 a = lyout[0][lane], b = lyout[1][lane];
        float* p0 = pooled + (size_t)g0 * 256 + 4 * lane;
        if (g0 == g1) {
            atomicAdd(p0 + 0, a.x + b.x); atomicAdd(p0 + 1, a.y + b.y);
            atomicAdd(p0 + 2, a.z + b.z); atomicAdd(p0 + 3, a.w + b.w);
            if (lane == 0) atomicAdd(cnt + g0, 2);
        } else {
            float* p1 = pooled + (size_t)g1 * 256 + 4 * lane;
            atomicAdd(p0 + 0, a.x); atomicAdd(p0 + 1, a.y);
            atomicAdd(p0 + 2, a.z); atomicAdd(p0 + 3, a.w);
            atomicAdd(p1 + 0, b.x); atomicAdd(p1 + 1, b.y);
            atomicAdd(p1 + 2, b.z); atomicAdd(p1 + 3, b.w);
            if (lane == 0) { atomicAdd(cnt + g0, 1); atomicAdd(cnt + g1, 1); }
        }
    }
}

// ---------------- pooled MLP + log_softmax: one wave per graph ----------------
__global__ void k_final(const float* __restrict__ pooled, const int* __restrict__ cnt,
                        const float* __restrict__ fc1W, const float* __restrict__ fc1b,
                        const float* __restrict__ fc2W, const float* __restrict__ fc2b,
                        float* __restrict__ out) {
    __shared__ float prow[4][256];
    __shared__ float zrow[4][64];
    int wid = threadIdx.x >> 6, lane = threadIdx.x & 63;
    int g = blockIdx.x * 4 + wid;
    float inv = 1.0f / fmaxf((float)cnt[g], 1.0f);
#pragma unroll
    for (int k = lane; k < 256; k += 64) prow[wid][k] = pooled[g * 256 + k] * inv;
    __syncthreads();
    float acc = fc1b[lane];
#pragma unroll 4
    for (int k = 0; k < 256; k++) acc += prow[wid][k] * fc1W[k * 64 + lane];
    zrow[wid][lane] = gelu_exact(acc);
    __syncthreads();
    float logit = fc2b[lane];
#pragma unroll 4
    for (int k = 0; k < 64; k++) logit += zrow[wid][k] * fc2W[k * 64 + lane];
    float mx = wave_max(logit);
    float se = wave_sum(__expf(logit - mx));
    out[g * NOUT + lane] = logit - mx - logf(se);
}

extern "C" void kernel_launch(void* const* d_in, const int* in_sizes, int n_in,
                              void* d_out, int out_size, void* d_ws, size_t ws_size,
                              hipStream_t stream) {
    const float* x     = (const float*)d_in[0];
    const int*   ei    = (const int*)d_in[1];
    const int*   batch = (const int*)d_in[2];
    const int*   gid   = (const int*)d_in[3];
    const float* gt    = (const float*)d_in[4];
    const float* inW   = (const float*)d_in[5];
    const float* inb   = (const float*)d_in[6];
    const float* inlng = (const float*)d_in[7];
    const float* inlnb = (const float*)d_in[8];
    const float* W0    = (const float*)d_in[9];
    const float* as0   = (const float*)d_in[10];
    const float* ad0   = (const float*)d_in[11];
    const float* b0    = (const float*)d_in[12];
    const float* ln0g  = (const float*)d_in[13];
    const float* ln0b  = (const float*)d_in[14];
    const float* W1    = (const float*)d_in[15];
    const float* as1   = (const float*)d_in[16];
    const float* ad1   = (const float*)d_in[17];
    const float* b1    = (const float*)d_in[18];
    const float* ln1g  = (const float*)d_in[19];
    const float* ln1b  = (const float*)d_in[20];
    const float* fc1W  = (const float*)d_in[21];
    const float* fc1b  = (const float*)d_in[22];
    const float* fc2W  = (const float*)d_in[23];
    const float* fc2b  = (const float*)d_in[24];
    float* out = (float*)d_out;

    char* ws = (char*)d_ws;
    size_t off = 0;
    auto alloc = [&](size_t bytes) {
        void* p = ws + off;
        off += (bytes + 255) / 256 * 256;
        return p;
    };
    unsigned short* Ain    = (unsigned short*)alloc((size_t)N_NODES * 192 * 2);
    unsigned short* h0bf   = (unsigned short*)alloc((size_t)N_NODES * 64 * 2);
    unsigned short* agg0bf = (unsigned short*)alloc((size_t)N_NODES * 256 * 2);
    unsigned short* h1bf   = (unsigned short*)alloc((size_t)N_NODES * 256 * 2);
    unsigned short* xlbf   = (unsigned short*)alloc((size_t)N_NODES * 256 * 2);
    unsigned short* inWpk  = (unsigned short*)alloc((size_t)192 * 64 * 2);
    unsigned short* W0pk   = (unsigned short*)alloc((size_t)64 * 256 * 2);
    unsigned short* W1pk   = (unsigned short*)alloc((size_t)256 * 256 * 2);
    float* us     = (float*)alloc((size_t)256 * 4);
    float* ud     = (float*)alloc((size_t)256 * 4);
    float* als0   = (float*)alloc((size_t)N_NODES * 4 * 4);
    float* ald0   = (float*)alloc((size_t)N_NODES * 4 * 4);
    float* als1   = (float*)alloc((size_t)N_NODES * 4 * 4);
    float* ald1   = (float*)alloc((size_t)N_NODES * 4 * 4);
    int*   rowptr = (int*)alloc((size_t)(N_NODES + 1) * 4);
    int*   cursor = (int*)alloc((size_t)N_NODES * 4);
    int*   csr    = (int*)alloc((size_t)ETOT * 4);
    int*   deg    = (int*)alloc((size_t)N_NODES * 4);
    float* pooled = (float*)alloc((size_t)NGRAPH * 256 * 4);
    int*   cnt    = (int*)alloc((size_t)NGRAPH * 4);

    hipMemsetAsync(deg, 0, (size_t)N_NODES * 4, stream);
    hipMemsetAsync(pooled, 0, (size_t)NGRAPH * 256 * 4, stream);
    hipMemsetAsync(cnt, 0, (size_t)NGRAPH * 4, stream);

    int eb = (ETOT + 255) / 256;
    k_count<<<eb, 256, 0, stream>>>(ei, deg);
    k_scan<<<1, 1024, 0, stream>>>(deg, rowptr, cursor);
    k_fill<<<eb, 256, 0, stream>>>(ei, cursor, csr);

    k_prep<<<N_NODES / 4, 256, 0, stream>>>(x, gid, gt, Ain);
    k_pack<<<(192 * 64 + 255) / 256, 256, 0, stream>>>(inW, inWpk, 192, 64);
    k_pack<<<(64 * 256 + 255) / 256, 256, 0, stream>>>(W0, W0pk, 64, 256);
    k_pack<<<(256 * 256 + 255) / 256, 256, 0, stream>>>(W1, W1pk, 256, 256);
    k_prep_u<<<1, 256, 0, stream>>>(W0, as0, ad0, us, ud);

    k_proj_in_mma<<<(N_NODES + 63) / 64, 256, 0, stream>>>(Ain, inWpk, inb, inlng, inlnb, h0bf);
    k_logits<<<N_NODES / 16, 256, 0, stream>>>(h0bf, us, ud, als0, ald0);
    k_agg0<<<N_NODES / 2, 256, 0, stream>>>(rowptr, csr, h0bf, als0, ald0, agg0bf);
    k_postgemm0<<<(N_NODES + 63) / 64, 256, 0, stream>>>(agg0bf, W0pk, b0, ln0g, ln0b, h1bf);
    k_proj_mma<<<N_NODES / 16, 256, 0, stream>>>(h1bf, W1pk, as1, ad1, xlbf, als1, ald1);
    k_agg1<<<N_NODES / 2, 256, 0, stream>>>(rowptr, csr, xlbf, als1, ald1, b1, ln1g, ln1b,
                                            h1bf, batch, pooled, cnt);
    k_final<<<NGRAPH / 4, 256, 0, stream>>>(pooled, cnt, fc1W, fc1b, fc2W, fc2b, out);
}